// Round 2
// baseline (109.419 us; speedup 1.0000x reference)
//
#include <hip/hip_runtime.h>

// TSClusteringLayer: q[n,k] = studentT(sum_f sqrt(sum_t (x[n,t,f]-c[k,t,f])^2)), row-normalized.
// x: (2048,128,32) f32, clusters: (32,128,32) f32, out: (2048,32) f32.
//
// v2: occupancy-first restructure.
//   Grid 512 blocks x 512 threads (8 waves). Block covers NB=4 n.
//   Wave w (0..7) handles t-range [w*16, w*16+16) for ALL 4 n.
//   Lane: f_grp=lane&7 (f0=4*f_grp), k_grp=(lane>>3)&7 (k0=4*k_grp).
//   Thread tile: 4n x 4k x 4f -> 64 fp32 accumulators.
//   Partial accs combined across the 8 waves with a 2-round LDS tree
//   (stride-65 float layout -> bank-conflict-free b32 accesses).
//   => 2 blocks/CU, 16 waves/CU (50% occupancy), 4 waves/SIMD.

#define T_DIM 128
#define F_DIM 32
#define K_DIM 32
#define TF (T_DIM * F_DIM)
#define NB 4           // n per block
#define TS 8           // t-splits (= waves per block)
#define TT (T_DIM/TS)  // 16 t per wave
#define SLOT_STRIDE 65 // floats; (lane*65+i)%32 distinct across lanes -> no bank conflicts

__global__ __launch_bounds__(512, 4) void tscluster_kernel(
    const float* __restrict__ x,
    const float* __restrict__ c,
    float* __restrict__ out)
{
    __shared__ float lds[4 * 64 * SLOT_STRIDE]; // 66560 B

    const int tid   = threadIdx.x;
    const int lane  = tid & 63;
    const int w     = tid >> 6;        // t-split index 0..7
    const int f_grp = lane & 7;
    const int k_grp = (lane >> 3) & 7;
    const int f0 = f_grp << 2;
    const int k0 = k_grp << 2;
    const int n0 = blockIdx.x * NB;

    const float* xp = x + (size_t)n0 * TF + w * TT * F_DIM + f0;
    const float* cp = c + (size_t)k0 * TF + w * TT * F_DIM + f0;

    float acc[NB][4][4];
    #pragma unroll
    for (int a = 0; a < NB; ++a)
        #pragma unroll
        for (int b = 0; b < 4; ++b)
            #pragma unroll
            for (int j = 0; j < 4; ++j)
                acc[a][b][j] = 0.0f;

    #pragma unroll 2
    for (int tt = 0; tt < TT; ++tt) {
        const int off = tt * F_DIM;

        float4 xv[NB], cv[4];
        #pragma unroll
        for (int a = 0; a < NB; ++a)
            xv[a] = *reinterpret_cast<const float4*>(xp + (size_t)a * TF + off);
        #pragma unroll
        for (int b = 0; b < 4; ++b)
            cv[b] = *reinterpret_cast<const float4*>(cp + (size_t)b * TF + off);

        float xs[NB][4], cs[4][4];
        #pragma unroll
        for (int a = 0; a < NB; ++a) {
            xs[a][0] = xv[a].x; xs[a][1] = xv[a].y; xs[a][2] = xv[a].z; xs[a][3] = xv[a].w;
        }
        #pragma unroll
        for (int b = 0; b < 4; ++b) {
            cs[b][0] = cv[b].x; cs[b][1] = cv[b].y; cs[b][2] = cv[b].z; cs[b][3] = cv[b].w;
        }

        #pragma unroll
        for (int a = 0; a < NB; ++a)
            #pragma unroll
            for (int b = 0; b < 4; ++b)
                #pragma unroll
                for (int j = 0; j < 4; ++j) {
                    const float d = xs[a][j] - cs[b][j];
                    acc[a][b][j] += d * d;
                }
    }

    // ---- combine partial accs across the 8 waves (tree via LDS) ----
    float* accf = &acc[0][0][0]; // 64 floats, all indexing below fully unrolled

    // round A: waves 4..7 -> slots 0..3; waves 0..3 add
    if (w >= 4) {
        float* dst = lds + ((size_t)(w - 4) * 64 + lane) * SLOT_STRIDE;
        #pragma unroll
        for (int i = 0; i < 64; ++i) dst[i] = accf[i];
    }
    __syncthreads();
    if (w < 4) {
        const float* src = lds + ((size_t)w * 64 + lane) * SLOT_STRIDE;
        #pragma unroll
        for (int i = 0; i < 64; ++i) accf[i] += src[i];
    }
    __syncthreads();
    // round B: waves 1..3 -> slots 0..2; wave 0 adds all three
    if (w >= 1 && w < 4) {
        float* dst = lds + ((size_t)(w - 1) * 64 + lane) * SLOT_STRIDE;
        #pragma unroll
        for (int i = 0; i < 64; ++i) dst[i] = accf[i];
    }
    __syncthreads();

    if (w == 0) {
        #pragma unroll
        for (int s = 0; s < 3; ++s) {
            const float* src = lds + ((size_t)s * 64 + lane) * SLOT_STRIDE;
            #pragma unroll
            for (int i = 0; i < 64; ++i) accf[i] += src[i];
        }

        // per-(n,k): partial distance = sum over this thread's 4 f of sqrt(acc)
        float dist[NB][4];
        #pragma unroll
        for (int a = 0; a < NB; ++a)
            #pragma unroll
            for (int b = 0; b < 4; ++b)
                dist[a][b] = sqrtf(acc[a][b][0]) + sqrtf(acc[a][b][1]) +
                             sqrtf(acc[a][b][2]) + sqrtf(acc[a][b][3]);

        // reduce over the 8 f_grp lanes (lane bits 0..2)
        #pragma unroll
        for (int off = 1; off < 8; off <<= 1)
            #pragma unroll
            for (int a = 0; a < NB; ++a)
                #pragma unroll
                for (int b = 0; b < 4; ++b)
                    dist[a][b] += __shfl_xor(dist[a][b], off, 64);

        // Student's t (alpha=1): q_un = (1 + d^2)^-1
        float qun[NB][4], qs[NB];
        #pragma unroll
        for (int a = 0; a < NB; ++a) {
            qs[a] = 0.0f;
            #pragma unroll
            for (int b = 0; b < 4; ++b) {
                qun[a][b] = 1.0f / (1.0f + dist[a][b] * dist[a][b]);
                qs[a] += qun[a][b];
            }
        }

        // reduce denom over the 8 k_grp lanes (lane bits 3..5)
        #pragma unroll
        for (int off = 8; off < 64; off <<= 1)
            #pragma unroll
            for (int a = 0; a < NB; ++a)
                qs[a] += __shfl_xor(qs[a], off, 64);

        if (f_grp == 0) {
            #pragma unroll
            for (int a = 0; a < NB; ++a) {
                float4 qv;
                qv.x = qun[a][0] / qs[a];
                qv.y = qun[a][1] / qs[a];
                qv.z = qun[a][2] / qs[a];
                qv.w = qun[a][3] / qs[a];
                *reinterpret_cast<float4*>(out + (size_t)(n0 + a) * K_DIM + k0) = qv;
            }
        }
    }
}

extern "C" void kernel_launch(void* const* d_in, const int* in_sizes, int n_in,
                              void* d_out, int out_size, void* d_ws, size_t ws_size,
                              hipStream_t stream) {
    const float* x = (const float*)d_in[0];
    const float* c = (const float*)d_in[1];
    float* out = (float*)d_out;
    tscluster_kernel<<<dim3(2048 / NB), dim3(512), 0, stream>>>(x, c, out);
}